// Round 14
// baseline (75.320 us; speedup 1.0000x reference)
//
#include <hip/hip_runtime.h>
#include <math.h>

#define NB 8
#define NQ 512
#define NK 512
#define NH 64
#define ND 256
#define QT 8     // q rows per score block / per PV block

typedef float f32x2 __attribute__((ext_vector_type(2)));
typedef float f32x4 __attribute__((ext_vector_type(4)));

#define EXP2(x) __builtin_amdgcn_exp2f(x)
#define RCP(x)  __builtin_amdgcn_rcpf(x)
#define SCALE2 2.8853900817779268f   // 2*log2(e) folded into projections
#define LOG2E  1.4426950408889634f

static __device__ __forceinline__ f32x2 sp2(float v) { return (f32x2){v, v}; }
static __device__ __forceinline__ f32x2 fma2(f32x2 a, f32x2 b, f32x2 c) {
    return __builtin_elementwise_fma(a, b, c);
}
static __device__ __forceinline__ f32x2 mk2(float x, float y) {
    return (f32x2){x, y};
}

// 4-way-rcp additive-attention partial: acc += N4/D4 over a 4-h group,
// packed over 2 adjacent k. eq/fq/w01 are wave-uniform scalars (SGPRs).
static __device__ __forceinline__ void score4(
    const f32x2 k0, const f32x2 k1, const f32x2 k2, const f32x2 k3,
    const f32x4 eqv, const f32x4 fqv, const float w01a, const float w01b,
    f32x2& acc)
{
    const f32x2 t0 = k0 * eqv.x;
    const f32x2 t1 = k1 * eqv.y;
    const f32x2 ua = t0 + t1 + 1.0f;
    const f32x2 da = fma2(t0, t1, ua);
    f32x2 na = fma2(k0, sp2(fqv.x), sp2(w01a));
    na = fma2(k1, sp2(fqv.y), na);
    const f32x2 t2 = k2 * eqv.z;
    const f32x2 t3 = k3 * eqv.w;
    const f32x2 ub = t2 + t3 + 1.0f;
    const f32x2 db = fma2(t2, t3, ub);
    f32x2 nb = fma2(k2, sp2(fqv.z), sp2(w01b));
    nb = fma2(k3, sp2(fqv.w), nb);
    const f32x2 D = da * db;
    f32x2 N = na * db;
    N = fma2(nb, da, N);
    const f32x2 rD = mk2(RCP(D.x), RCP(D.y));
    acc = fma2(N, rD, acc);
}

// ---------------- projection + exp2:
//  q rows -> qside[row][hc][{eq0..3, fq0..3}]  (fq = w_v[h^1]*eq), 32B units
//  k rows -> Ekp[b][h][k] (transposed)
// block 0 also emits w01g[32] (pairwise w sums) and wsumg (sum of w_v).
__global__ __launch_bounds__(256, 4) void proj_kernel(
    const float* __restrict__ query, const float* __restrict__ key,
    const float* __restrict__ Wq, const float* __restrict__ Wk,
    const float* __restrict__ w_v,
    float* __restrict__ qside, float* __restrict__ Ekp,
    float* __restrict__ w01g, float* __restrict__ wsumg)
{
    __shared__ __align__(16) float insT[ND][12];   // 12 KB
    __shared__ float pacc[3][4][NH][2];            // 6 KB wave partials
    const int t = threadIdx.x;
    const bool isK = blockIdx.x >= 512;
    const float* __restrict__ in = isK ? key : query;
    const float* __restrict__ W  = isK ? Wk : Wq;
    const int rowbase = (blockIdx.x & 511) * 8;

    {   // stage 8 rows x 256 d, transposed
        const int r = t & 7, c = (t >> 3) * 8;
        const float* src = in + (size_t)(rowbase + r) * ND + c;
        const f32x4 v0 = *(const f32x4*)src;
        const f32x4 v1 = *(const f32x4*)(src + 4);
        insT[c + 0][r] = v0.x; insT[c + 1][r] = v0.y;
        insT[c + 2][r] = v0.z; insT[c + 3][r] = v0.w;
        insT[c + 4][r] = v1.x; insT[c + 5][r] = v1.y;
        insT[c + 6][r] = v1.z; insT[c + 7][r] = v1.w;
    }
    __syncthreads();

    const int lane = t & 63;          // lane = h
    const int w    = t >> 6;          // wave = d-quarter
    const int d0   = w * 64;

    f32x2 acc[4] = {{0.f,0.f},{0.f,0.f},{0.f,0.f},{0.f,0.f}};
    for (int dd = 0; dd < 64; ++dd) {
        const int d = d0 + dd;
        const float wv = W[(size_t)d * NH + lane];         // coalesced L2
        const f32x4 rA = *(const f32x4*)&insT[d][0];       // uniform b128
        const f32x4 rB = *(const f32x4*)&insT[d][4];
        acc[0] = fma2(mk2(rA.x, rA.y), sp2(wv), acc[0]);
        acc[1] = fma2(mk2(rA.z, rA.w), sp2(wv), acc[1]);
        acc[2] = fma2(mk2(rB.x, rB.y), sp2(wv), acc[2]);
        acc[3] = fma2(mk2(rB.z, rB.w), sp2(wv), acc[3]);
    }
    if (w > 0) {
        #pragma unroll
        for (int rp = 0; rp < 4; ++rp)
            *(f32x2*)&pacc[w - 1][rp][lane][0] = acc[rp];
    }
    __syncthreads();
    if (w == 0) {
        float e[8];
        #pragma unroll
        for (int rp = 0; rp < 4; ++rp) {
            f32x2 a = acc[rp];
            a += *(const f32x2*)&pacc[0][rp][lane][0];
            a += *(const f32x2*)&pacc[1][rp][lane][0];
            a += *(const f32x2*)&pacc[2][rp][lane][0];
            e[2 * rp] = a.x; e[2 * rp + 1] = a.y;
        }
        #pragma unroll
        for (int j = 0; j < 8; ++j) {
            const float x = fminf(fmaxf(e[j] * SCALE2, -30.f), 30.f);
            e[j] = EXP2(x);
        }
        if (!isK) {
            const float wx = w_v[lane ^ 1];
            #pragma unroll
            for (int j = 0; j < 8; ++j) {
                const int g = rowbase + j;
                float* dst = qside + ((size_t)g * 16 + (lane >> 2)) * 8 + (lane & 3);
                dst[0] = e[j];
                dst[4] = wx * e[j];
            }
        } else {
            #pragma unroll
            for (int j = 0; j < 8; ++j) {
                const int g = rowbase + j;
                const int bb = g >> 9, kk = g & 511;
                Ekp[((size_t)bb * NH + lane) * NK + kk] = e[j];
            }
        }
    }
    if (blockIdx.x == 0) {
        if (t < 32) w01g[t] = w_v[2 * t] + w_v[2 * t + 1];
        if (t == 64) {
            float s = 0.f;
            for (int h = 0; h < NH; ++h) s += w_v[h];
            wsumg[0] = s;
        }
    }
}

// ---------------- kernel A: score + softmax -> normalized probs Pg[b][q][k]
// grid = 512 blocks (XCD-swizzled) x 1024 thr (16 waves) = 2 blocks/CU
// = 32 waves/CU = 8 waves/SIMD. Thread = 2 adjacent k (kp=t&255) x 2 rows
// (rh=t>>8 in 0..3). Tiny LDS, tiny register state -> no spill pressure.
__global__ __launch_bounds__(1024, 4) void score_kernel(
    const float* __restrict__ qside, const float* __restrict__ Ekp,
    const unsigned char* __restrict__ mask,
    const float* __restrict__ w01g, const float* __restrict__ wsumg,
    float* __restrict__ Pg)
{
    __shared__ float reds[QT][4];   // per-(row, k-quarter-wave) partial sums

    const int t    = threadIdx.x;
    const int lane = t & 63;
    const int w    = t >> 6;                   // 0..15
    // XCD swizzle (512%8==0, bijective): one batch per XCD.
    const int bid  = ((int)(blockIdx.x & 7) << 6) | ((int)blockIdx.x >> 3);
    const int b    = bid >> 6;
    const int q0   = (bid & 63) * QT;
    const int rh   = __builtin_amdgcn_readfirstlane(t >> 8);  // 0..3
    const int kp   = t & 255;

    const float wsumL = wsumg[0] * LOG2E;
    const float* __restrict__ qs  = qside + (size_t)(b * NQ + q0 + rh * 2) * 128;
    const float* __restrict__ ekc = Ekp + (size_t)b * NH * NK + 2 * kp;

    f32x2 eka[4];
    #pragma unroll
    for (int j = 0; j < 4; ++j) eka[j] = *(const f32x2*)&ekc[(size_t)j * NK];

    f32x2 acc[2] = {{0.f,0.f},{0.f,0.f}};

    for (int hc = 0; hc < 16; ++hc) {
        const f32x2 k0 = eka[0], k1 = eka[1], k2 = eka[2], k3 = eka[3];
        if (hc < 15) {   // roll-forward prefetch (R10 pattern)
            #pragma unroll
            for (int j = 0; j < 4; ++j)
                eka[j] = *(const f32x2*)&ekc[(size_t)(4 * (hc + 1) + j) * NK];
        }
        const float wa = w01g[2 * hc], wb = w01g[2 * hc + 1];
        #pragma unroll
        for (int r = 0; r < 2; ++r) {
            const f32x4 eqv = *(const f32x4*)&qs[r * 128 + hc * 8];     // s_load
            const f32x4 fqv = *(const f32x4*)&qs[r * 128 + hc * 8 + 4]; // s_load
            score4(k0, k1, k2, k3, eqv, fqv, wa, wb, acc[r]);
        }
    }

    // ---- mask + exp (no max-subtraction: |score| <= sum|w_h| ~ 6.4)
    const unsigned char* __restrict__ mb =
        mask + (size_t)(b * NQ + q0 + rh * 2) * NK + 2 * kp;
    f32x2 p[2];
    #pragma unroll
    for (int r = 0; r < 2; ++r) {
        f32x2 arg = fma2(acc[r], sp2(-2.f * LOG2E), sp2(wsumL));
        const unsigned short m = *(const unsigned short*)(mb + (size_t)r * NK);
        if (m & 0x00ff) arg.x = -__builtin_inff();
        if (m & 0xff00) arg.y = -__builtin_inff();
        p[r] = mk2(EXP2(arg.x), EXP2(arg.y));
    }

    // ---- row sums: wave shuffle + cross-wave LDS (4 k-quarter waves/row)
    #pragma unroll
    for (int r = 0; r < 2; ++r) {
        float s = p[r].x + p[r].y;
        #pragma unroll
        for (int off = 32; off; off >>= 1) s += __shfl_xor(s, off, 64);
        if (lane == 0) reds[rh * 2 + r][w & 3] = s;
    }
    __syncthreads();
    #pragma unroll
    for (int r = 0; r < 2; ++r) {
        const f32x4 sv = *(const f32x4*)&reds[rh * 2 + r][0];
        const float gsum = (sv.x + sv.y) + (sv.z + sv.w);
        p[r] = p[r] * RCP(gsum);
        *(f32x2*)&Pg[(size_t)(b * NQ + q0 + rh * 2 + r) * NK + 2 * kp] = p[r];
    }
}

// ---------------- kernel B: PV. out[8 rows][128 d-half] per block.
// grid = NB*64*2 = 1024 blocks (XCD-swizzled) x 512 thr (8 waves)
// = 4 blocks/CU = 32 waves/CU. Wave = 64-k slice (kq=0..7); lane = f32x2 of d.
// P read via wave-uniform loads (scalarizable); V streamed once per block.
__global__ __launch_bounds__(512, 4) void pv_kernel(
    const float* __restrict__ Pg, const float* __restrict__ value,
    float* __restrict__ out)
{
    __shared__ __align__(16) float pacc[7][QT][128];   // 28 KB

    const int t    = threadIdx.x;
    const int lane = t & 63;
    const int kq   = __builtin_amdgcn_readfirstlane(t >> 6);   // 0..7
    // XCD swizzle (1024%8==0, bijective): one batch per XCD.
    const int bid  = ((int)(blockIdx.x & 7) << 7) | ((int)blockIdx.x >> 3);
    const int b    = bid >> 7;
    const int rem  = bid & 127;
    const int q0   = (rem >> 1) * QT;
    const int dh   = rem & 1;
    const int dcol = dh * 128 + 2 * lane;

    const float* __restrict__ Pb = Pg + (size_t)(b * NQ + q0) * NK;
    const float* __restrict__ vb = value + ((size_t)b * NK + kq * 64) * ND + dcol;

    f32x2 a[QT];
    #pragma unroll
    for (int r = 0; r < QT; ++r) a[r] = (f32x2){0.f, 0.f};

    for (int kk = 0; kk < 64; kk += 4) {
        const int kbase = kq * 64 + kk;
        const f32x2 v0 = *(const f32x2*)&vb[(size_t)(kk + 0) * ND];
        const f32x2 v1 = *(const f32x2*)&vb[(size_t)(kk + 1) * ND];
        const f32x2 v2 = *(const f32x2*)&vb[(size_t)(kk + 2) * ND];
        const f32x2 v3 = *(const f32x2*)&vb[(size_t)(kk + 3) * ND];
        #pragma unroll
        for (int r = 0; r < QT; ++r) {
            const f32x4 P = *(const f32x4*)&Pb[(size_t)r * NK + kbase]; // uniform
            a[r] = fma2(sp2(P.x), v0, a[r]);
            a[r] = fma2(sp2(P.y), v1, a[r]);
            a[r] = fma2(sp2(P.z), v2, a[r]);
            a[r] = fma2(sp2(P.w), v3, a[r]);
        }
    }

    if (kq > 0) {
        #pragma unroll
        for (int r = 0; r < QT; ++r)
            *(f32x2*)&pacc[kq - 1][r][2 * lane] = a[r];
    }
    __syncthreads();
    if (kq == 0) {
        #pragma unroll
        for (int r = 0; r < QT; ++r) {
            f32x2 v = a[r];
            #pragma unroll
            for (int j = 0; j < 7; ++j)
                v += *(const f32x2*)&pacc[j][r][2 * lane];
            *(f32x2*)&out[(size_t)(b * NQ + q0 + r) * ND + dcol] = v;
        }
    }
}

extern "C" void kernel_launch(void* const* d_in, const int* in_sizes, int n_in,
                              void* d_out, int out_size, void* d_ws, size_t ws_size,
                              hipStream_t stream) {
    const float* key   = (const float*)d_in[0];
    const float* query = (const float*)d_in[1];
    const float* value = (const float*)d_in[2];
    const unsigned char* mask = (const unsigned char*)d_in[3];
    const float* Wk  = (const float*)d_in[4];
    const float* Wq  = (const float*)d_in[5];
    const float* w_v = (const float*)d_in[6];
    float* out = (float*)d_out;

    float* Ekp   = (float*)d_ws;                        // [NB, NH, NK]   1 MB
    float* qside = Ekp + (size_t)NB * NH * NK;          // [NB*NQ, 128]   2 MB
    float* w01g  = qside + (size_t)NB * NQ * 128;       // [32]
    float* wsumg = w01g + 32;                           // [1]
    float* Pg    = wsumg + 31;                          // [NB, NQ, NK]   8.4 MB (16B-aligned)

    proj_kernel<<<1024, 256, 0, stream>>>(query, key, Wq, Wk, w_v,
                                          qside, Ekp, w01g, wsumg);
    score_kernel<<<512, 1024, 0, stream>>>(qside, Ekp, mask, w01g, wsumg, Pg);
    pv_kernel<<<NB * 64 * 2, 512, 0, stream>>>(Pg, value, out);
}

// Round 15
// 54.412 us; speedup vs baseline: 1.3842x; 1.3842x over previous
//
#include <hip/hip_runtime.h>
#include <math.h>

#define NB 8
#define NQ 512
#define NK 512
#define NH 64
#define ND 256
#define QT 8     // q rows per block
#define KH 256   // k per block (half of NK)

typedef float f32x2 __attribute__((ext_vector_type(2)));
typedef float f32x4 __attribute__((ext_vector_type(4)));

#define EXP2(x) __builtin_amdgcn_exp2f(x)
#define RCP(x)  __builtin_amdgcn_rcpf(x)
#define SCALE2 2.8853900817779268f   // 2*log2(e) folded into projections
#define LOG2E  1.4426950408889634f

static __device__ __forceinline__ f32x2 sp2(float v) { return (f32x2){v, v}; }
static __device__ __forceinline__ f32x2 fma2(f32x2 a, f32x2 b, f32x2 c) {
    return __builtin_elementwise_fma(a, b, c);
}
static __device__ __forceinline__ f32x2 mk2(float x, float y) {
    return (f32x2){x, y};
}

// 4-way-rcp additive-attention partial: acc += N4/D4 over a 4-h group,
// packed over 2 adjacent k. eq/fq/w01 are wave-uniform scalars (SGPRs).
static __device__ __forceinline__ void score4(
    const f32x2 k0, const f32x2 k1, const f32x2 k2, const f32x2 k3,
    const f32x4 eqv, const f32x4 fqv, const float w01a, const float w01b,
    f32x2& acc)
{
    const f32x2 t0 = k0 * eqv.x;
    const f32x2 t1 = k1 * eqv.y;
    const f32x2 ua = t0 + t1 + 1.0f;
    const f32x2 da = fma2(t0, t1, ua);
    f32x2 na = fma2(k0, sp2(fqv.x), sp2(w01a));
    na = fma2(k1, sp2(fqv.y), na);
    const f32x2 t2 = k2 * eqv.z;
    const f32x2 t3 = k3 * eqv.w;
    const f32x2 ub = t2 + t3 + 1.0f;
    const f32x2 db = fma2(t2, t3, ub);
    f32x2 nb = fma2(k2, sp2(fqv.z), sp2(w01b));
    nb = fma2(k3, sp2(fqv.w), nb);
    const f32x2 D = da * db;
    f32x2 N = na * db;
    N = fma2(nb, da, N);
    const f32x2 rD = mk2(RCP(D.x), RCP(D.y));
    acc = fma2(N, rD, acc);
}

// ---------------- projection + exp2:
//  q rows -> qside[row][hc][{eq0..3, fq0..3}]  (fq = w_v[h^1]*eq), 32B units
//  k rows -> Ekp[b][h][k] (transposed)
// block 0 also emits w01g[32] (pairwise w sums) and wsumg (sum of w_v).
__global__ __launch_bounds__(256, 4) void proj_kernel(
    const float* __restrict__ query, const float* __restrict__ key,
    const float* __restrict__ Wq, const float* __restrict__ Wk,
    const float* __restrict__ w_v,
    float* __restrict__ qside, float* __restrict__ Ekp,
    float* __restrict__ w01g, float* __restrict__ wsumg)
{
    __shared__ __align__(16) float insT[ND][12];   // 12 KB
    __shared__ float pacc[3][4][NH][2];            // 6 KB wave partials
    const int t = threadIdx.x;
    const bool isK = blockIdx.x >= 512;
    const float* __restrict__ in = isK ? key : query;
    const float* __restrict__ W  = isK ? Wk : Wq;
    const int rowbase = (blockIdx.x & 511) * 8;

    {   // stage 8 rows x 256 d, transposed
        const int r = t & 7, c = (t >> 3) * 8;
        const float* src = in + (size_t)(rowbase + r) * ND + c;
        const f32x4 v0 = *(const f32x4*)src;
        const f32x4 v1 = *(const f32x4*)(src + 4);
        insT[c + 0][r] = v0.x; insT[c + 1][r] = v0.y;
        insT[c + 2][r] = v0.z; insT[c + 3][r] = v0.w;
        insT[c + 4][r] = v1.x; insT[c + 5][r] = v1.y;
        insT[c + 6][r] = v1.z; insT[c + 7][r] = v1.w;
    }
    __syncthreads();

    const int lane = t & 63;          // lane = h
    const int w    = t >> 6;          // wave = d-quarter
    const int d0   = w * 64;

    f32x2 acc[4] = {{0.f,0.f},{0.f,0.f},{0.f,0.f},{0.f,0.f}};
    for (int dd = 0; dd < 64; ++dd) {
        const int d = d0 + dd;
        const float wv = W[(size_t)d * NH + lane];         // coalesced L2
        const f32x4 rA = *(const f32x4*)&insT[d][0];       // uniform b128
        const f32x4 rB = *(const f32x4*)&insT[d][4];
        acc[0] = fma2(mk2(rA.x, rA.y), sp2(wv), acc[0]);
        acc[1] = fma2(mk2(rA.z, rA.w), sp2(wv), acc[1]);
        acc[2] = fma2(mk2(rB.x, rB.y), sp2(wv), acc[2]);
        acc[3] = fma2(mk2(rB.z, rB.w), sp2(wv), acc[3]);
    }
    if (w > 0) {
        #pragma unroll
        for (int rp = 0; rp < 4; ++rp)
            *(f32x2*)&pacc[w - 1][rp][lane][0] = acc[rp];
    }
    __syncthreads();
    if (w == 0) {
        float e[8];
        #pragma unroll
        for (int rp = 0; rp < 4; ++rp) {
            f32x2 a = acc[rp];
            a += *(const f32x2*)&pacc[0][rp][lane][0];
            a += *(const f32x2*)&pacc[1][rp][lane][0];
            a += *(const f32x2*)&pacc[2][rp][lane][0];
            e[2 * rp] = a.x; e[2 * rp + 1] = a.y;
        }
        #pragma unroll
        for (int j = 0; j < 8; ++j) {
            const float x = fminf(fmaxf(e[j] * SCALE2, -30.f), 30.f);
            e[j] = EXP2(x);
        }
        if (!isK) {
            const float wx = w_v[lane ^ 1];
            #pragma unroll
            for (int j = 0; j < 8; ++j) {
                const int g = rowbase + j;
                float* dst = qside + ((size_t)g * 16 + (lane >> 2)) * 8 + (lane & 3);
                dst[0] = e[j];
                dst[4] = wx * e[j];
            }
        } else {
            #pragma unroll
            for (int j = 0; j < 8; ++j) {
                const int g = rowbase + j;
                const int bb = g >> 9, kk = g & 511;
                Ekp[((size_t)bb * NH + lane) * NK + kk] = e[j];
            }
        }
    }
    if (blockIdx.x == 0) {
        if (t < 32) w01g[t] = w_v[2 * t] + w_v[2 * t + 1];
        if (t == 64) {
            float s = 0.f;
            for (int h = 0; h < NH; ++h) s += w_v[h];
            wsumg[0] = s;
        }
    }
}

// ---------------- kernel A: score + UNNORMALIZED softmax + PV-partial for one
// k-half. grid = NB*64*2 = 1024 blocks (XCD-swizzled) x 512 thr (8 waves)
// = 4 blocks/CU = 32 waves/CU. Score: thread = 2 adjacent k x 2 rows
// (rq = t>>7 in 0..3), eA/eB double-rolled prefetch (the R10-proven shape).
// PV: wave = (kq 0..3 of 64k, dh 0..1); writes pvp[half] + row-sums.
__global__ __launch_bounds__(512, 4) void scorepv_kernel(
    const float* __restrict__ qside, const float* __restrict__ Ekp,
    const float* __restrict__ value, const unsigned char* __restrict__ mask,
    const float* __restrict__ w01g, const float* __restrict__ wsumg,
    float* __restrict__ pvp, float* __restrict__ sums)
{
    __shared__ __align__(16) float ps[QT][KH];        // 8 KB unnormalized p
    __shared__ __align__(16) float pacc[3][QT][ND];   // 24 KB PV partials
    __shared__ float reds[QT][2];

    const int t    = threadIdx.x;
    const int lane = t & 63;
    const int w    = t >> 6;
    // XCD swizzle (1024%8==0, bijective): one batch per XCD.
    const int bid  = ((int)(blockIdx.x & 7) << 7) | ((int)blockIdx.x >> 3);
    const int b    = bid >> 7;
    const int rem  = bid & 127;
    const int q0   = (rem >> 1) * QT;
    const int half = rem & 1;
    const int rq   = __builtin_amdgcn_readfirstlane(t >> 7);  // 0..3
    const int kpl  = t & 127;                 // k-pair within half
    const int k    = half * KH + 2 * kpl;     // global k of this thread

    const float wsumL = wsumg[0] * LOG2E;
    const float* __restrict__ qs  = qside + (size_t)(b * NQ + q0 + rq * 2) * 128;
    const float* __restrict__ ekc = Ekp + (size_t)b * NH * NK + k;

    f32x2 eA[4], eB[4];
    #pragma unroll
    for (int j = 0; j < 4; ++j) eA[j] = *(const f32x2*)&ekc[(size_t)j * NK];
    #pragma unroll
    for (int j = 0; j < 4; ++j) eB[j] = *(const f32x2*)&ekc[(size_t)(4 + j) * NK];

    f32x2 acc[2] = {{0.f,0.f},{0.f,0.f}};

    for (int hc = 0; hc < 16; hc += 2) {
        {   // even chunk: consume eA, prefetch hc+2 into eA
            const f32x2 k0 = eA[0], k1 = eA[1], k2 = eA[2], k3 = eA[3];
            if (hc + 2 < 16) {
                #pragma unroll
                for (int j = 0; j < 4; ++j)
                    eA[j] = *(const f32x2*)&ekc[(size_t)(4 * (hc + 2) + j) * NK];
            }
            const float wa = w01g[2 * hc], wb = w01g[2 * hc + 1];
            #pragma unroll
            for (int r = 0; r < 2; ++r) {
                const f32x4 eqv = *(const f32x4*)&qs[r * 128 + hc * 8];     // s_load
                const f32x4 fqv = *(const f32x4*)&qs[r * 128 + hc * 8 + 4]; // s_load
                score4(k0, k1, k2, k3, eqv, fqv, wa, wb, acc[r]);
            }
        }
        {   // odd chunk: consume eB, prefetch hc+3 into eB
            const f32x2 k0 = eB[0], k1 = eB[1], k2 = eB[2], k3 = eB[3];
            if (hc + 3 < 16) {
                #pragma unroll
                for (int j = 0; j < 4; ++j)
                    eB[j] = *(const f32x2*)&ekc[(size_t)(4 * (hc + 3) + j) * NK];
            }
            const float wa = w01g[2 * hc + 2], wb = w01g[2 * hc + 3];
            #pragma unroll
            for (int r = 0; r < 2; ++r) {
                const f32x4 eqv = *(const f32x4*)&qs[r * 128 + (hc + 1) * 8];
                const f32x4 fqv = *(const f32x4*)&qs[r * 128 + (hc + 1) * 8 + 4];
                score4(k0, k1, k2, k3, eqv, fqv, wa, wb, acc[r]);
            }
        }
    }

    // ---- mask + exp, UNNORMALIZED (|score| <= sum|w_h| ~ 6.4, no max needed)
    const unsigned char* __restrict__ mb =
        mask + (size_t)(b * NQ + q0 + rq * 2) * NK + k;
    f32x2 p[2];
    #pragma unroll
    for (int r = 0; r < 2; ++r) {
        f32x2 arg = fma2(acc[r], sp2(-2.f * LOG2E), sp2(wsumL));
        const unsigned short m = *(const unsigned short*)(mb + (size_t)r * NK);
        if (m & 0x00ff) arg.x = -__builtin_inff();
        if (m & 0xff00) arg.y = -__builtin_inff();
        p[r] = mk2(EXP2(arg.x), EXP2(arg.y));
        *(f32x2*)&ps[rq * 2 + r][2 * kpl] = p[r];
    }

    // ---- per-row partial sums over this k-half (2 waves per row)
    #pragma unroll
    for (int r = 0; r < 2; ++r) {
        float s = p[r].x + p[r].y;
        #pragma unroll
        for (int off = 32; off; off >>= 1) s += __shfl_xor(s, off, 64);
        if (lane == 0) reds[rq * 2 + r][w & 1] = s;
    }
    __syncthreads();
    if (lane == 0 && (w & 1) == 0) {
        #pragma unroll
        for (int r = 0; r < 2; ++r) {
            const int row = rq * 2 + r;
            sums[((size_t)half * NB + b) * NQ + q0 + row] =
                reds[row][0] + reds[row][1];
        }
    }

    // ---- PV partial: wave = (kq 0..3, dh 0..1); lane owns f32x2 of d
    const int kq   = w >> 1;
    const int dh   = w & 1;
    const int dcol = dh * 128 + 2 * lane;
    f32x2 a[QT];
    #pragma unroll
    for (int r = 0; r < QT; ++r) a[r] = (f32x2){0.f, 0.f};

    const float* __restrict__ vb =
        value + ((size_t)b * NK + half * KH + kq * 64) * ND + dcol;
    for (int kk = 0; kk < 64; kk += 4) {
        const int kbase = kq * 64 + kk;
        const f32x2 v0 = *(const f32x2*)&vb[(size_t)(kk + 0) * ND];
        const f32x2 v1 = *(const f32x2*)&vb[(size_t)(kk + 1) * ND];
        const f32x2 v2 = *(const f32x2*)&vb[(size_t)(kk + 2) * ND];
        const f32x2 v3 = *(const f32x2*)&vb[(size_t)(kk + 3) * ND];
        #pragma unroll
        for (int r = 0; r < QT; ++r) {
            const f32x4 P = *(const f32x4*)&ps[r][kbase];   // uniform b128
            a[r] = fma2(sp2(P.x), v0, a[r]);
            a[r] = fma2(sp2(P.y), v1, a[r]);
            a[r] = fma2(sp2(P.z), v2, a[r]);
            a[r] = fma2(sp2(P.w), v3, a[r]);
        }
    }

    if (kq > 0) {
        #pragma unroll
        for (int r = 0; r < QT; ++r)
            *(f32x2*)&pacc[kq - 1][r][dcol] = a[r];
    }
    __syncthreads();
    if (kq == 0) {
        float* __restrict__ po =
            pvp + (((size_t)half * NB + b) * NQ + q0) * ND + dcol;
        #pragma unroll
        for (int r = 0; r < QT; ++r) {
            f32x2 v = a[r];
            v += *(const f32x2*)&pacc[0][r][dcol];
            v += *(const f32x2*)&pacc[1][r][dcol];
            v += *(const f32x2*)&pacc[2][r][dcol];
            *(f32x2*)&po[(size_t)r * ND] = v;
        }
    }
}

// ---------------- kernel C: combine halves. out = (pv0+pv1) * rcp(s0+s1).
// grid = 2048 blocks (XCD-swizzled) x 256 thr; block = 2 q-rows.
__global__ __launch_bounds__(256, 4) void combine_kernel(
    const float* __restrict__ pvp, const float* __restrict__ sums,
    float* __restrict__ out)
{
    const int t   = threadIdx.x;
    const int bid = ((int)(blockIdx.x & 7) << 8) | ((int)blockIdx.x >> 3);
    const int b   = bid >> 8;
    const int q   = (bid & 255) * 2 + (t >> 7);
    const int d   = (t & 127) * 2;

    const float s0 = sums[((size_t)0 * NB + b) * NQ + q];
    const float s1 = sums[((size_t)1 * NB + b) * NQ + q];
    const float rs = RCP(s0 + s1);
    const f32x2 pv0 = *(const f32x2*)&pvp[(((size_t)0 * NB + b) * NQ + q) * ND + d];
    const f32x2 pv1 = *(const f32x2*)&pvp[(((size_t)1 * NB + b) * NQ + q) * ND + d];
    const f32x2 v = (pv0 + pv1) * rs;
    *(f32x2*)&out[((size_t)b * NQ + q) * ND + d] = v;
}

extern "C" void kernel_launch(void* const* d_in, const int* in_sizes, int n_in,
                              void* d_out, int out_size, void* d_ws, size_t ws_size,
                              hipStream_t stream) {
    const float* key   = (const float*)d_in[0];
    const float* query = (const float*)d_in[1];
    const float* value = (const float*)d_in[2];
    const unsigned char* mask = (const unsigned char*)d_in[3];
    const float* Wk  = (const float*)d_in[4];
    const float* Wq  = (const float*)d_in[5];
    const float* w_v = (const float*)d_in[6];
    float* out = (float*)d_out;

    float* Ekp   = (float*)d_ws;                        // [NB, NH, NK]     1 MB
    float* qside = Ekp + (size_t)NB * NH * NK;          // [NB*NQ, 128]     2 MB
    float* w01g  = qside + (size_t)NB * NQ * 128;       // [32]
    float* wsumg = w01g + 32;                           // [1]
    float* pvp   = w01g + 64;                           // [2, NB, NQ, ND]  8 MB
    float* sums  = pvp + (size_t)2 * NB * NQ * ND;      // [2, NB, NQ]      32 KB

    proj_kernel<<<1024, 256, 0, stream>>>(query, key, Wq, Wk, w_v,
                                          qside, Ekp, w01g, wsumg);
    scorepv_kernel<<<NB * 64 * 2, 512, 0, stream>>>(qside, Ekp, value, mask,
                                                    w01g, wsumg, pvp, sums);
    combine_kernel<<<NB * 256, 256, 0, stream>>>(pvp, sums, out);
}

// Round 17
// 46.438 us; speedup vs baseline: 1.6219x; 1.1717x over previous
//
#include <hip/hip_runtime.h>
#include <math.h>

#define NB 8
#define NQ 512
#define NK 512
#define NH 64
#define ND 256
#define QT 8     // q rows per score block

typedef float f32x2 __attribute__((ext_vector_type(2)));
typedef float f32x4 __attribute__((ext_vector_type(4)));
typedef _Float16 f16x2 __attribute__((ext_vector_type(2)));
typedef _Float16 f16x8 __attribute__((ext_vector_type(8)));

#define EXP2(x) __builtin_amdgcn_exp2f(x)
#define RCP(x)  __builtin_amdgcn_rcpf(x)
#define SCALE2 2.8853900817779268f   // 2*log2(e) folded into projections
#define LOG2E  1.4426950408889634f

static __device__ __forceinline__ f32x2 sp2(float v) { return (f32x2){v, v}; }
static __device__ __forceinline__ f32x2 fma2(f32x2 a, f32x2 b, f32x2 c) {
    return __builtin_elementwise_fma(a, b, c);
}
static __device__ __forceinline__ f32x2 mk2(float x, float y) {
    return (f32x2){x, y};
}
static __device__ __forceinline__ f16x2 cvt2h(float a, float b) {
#if __has_builtin(__builtin_amdgcn_cvt_pkrtz)
    return __builtin_bit_cast(f16x2, __builtin_amdgcn_cvt_pkrtz(a, b));
#else
    return (f16x2){(_Float16)a, (_Float16)b};
#endif
}

// 4-way-rcp additive-attention partial: acc += N4/D4 over a 4-h group,
// packed over 2 adjacent k. eq/fq/w01 are wave-uniform scalars (SGPRs).
static __device__ __forceinline__ void score4(
    const f32x2 k0, const f32x2 k1, const f32x2 k2, const f32x2 k3,
    const f32x4 eqv, const f32x4 fqv, const float w01a, const float w01b,
    f32x2& acc)
{
    const f32x2 t0 = k0 * eqv.x;
    const f32x2 t1 = k1 * eqv.y;
    const f32x2 ua = t0 + t1 + 1.0f;
    const f32x2 da = fma2(t0, t1, ua);
    f32x2 na = fma2(k0, sp2(fqv.x), sp2(w01a));
    na = fma2(k1, sp2(fqv.y), na);
    const f32x2 t2 = k2 * eqv.z;
    const f32x2 t3 = k3 * eqv.w;
    const f32x2 ub = t2 + t3 + 1.0f;
    const f32x2 db = fma2(t2, t3, ub);
    f32x2 nb = fma2(k2, sp2(fqv.z), sp2(w01b));
    nb = fma2(k3, sp2(fqv.w), nb);
    const f32x2 D = da * db;
    f32x2 N = na * db;
    N = fma2(nb, da, N);
    const f32x2 rD = mk2(RCP(D.x), RCP(D.y));
    acc = fma2(N, rD, acc);
}

// ---------------- projection + exp2 (+ V f16 transpose):
//  blocks [0,512):    q rows -> qside[row][hc][{eq0..3, fq0..3}]
//  blocks [512,1024): k rows -> Ekp[b][h][k] (transposed)
//  blocks [1024,1536): V -> VhT[b][d][k] f16 (transposed for MFMA B-frags)
__global__ __launch_bounds__(256, 4) void proj_kernel(
    const float* __restrict__ query, const float* __restrict__ key,
    const float* __restrict__ value,
    const float* __restrict__ Wq, const float* __restrict__ Wk,
    const float* __restrict__ w_v,
    float* __restrict__ qside, float* __restrict__ Ekp,
    float* __restrict__ w01g, float* __restrict__ wsumg,
    _Float16* __restrict__ VhT)
{
    const int t = threadIdx.x;

    if (blockIdx.x >= 1024) {   // ---- V transpose + f16: 8 k-rows x 256 d
        const int vbase = ((int)blockIdx.x - 1024) * 8;
        const int bb = vbase >> 9, k0 = vbase & 511;
        const int d = t;
        const float* __restrict__ vsrc = value + ((size_t)bb * NK + k0) * ND + d;
        float v[8];
        #pragma unroll
        for (int j = 0; j < 8; ++j) v[j] = vsrc[(size_t)j * ND];   // coalesced
        f16x8 hv;
        #pragma unroll
        for (int j = 0; j < 4; ++j) {
            const f16x2 h = cvt2h(v[2 * j], v[2 * j + 1]);
            hv[2 * j] = h.x; hv[2 * j + 1] = h.y;
        }
        *(f16x8*)&VhT[((size_t)bb * ND + d) * NK + k0] = hv;
        return;
    }

    __shared__ __align__(16) float insT[ND][12];   // 12 KB
    __shared__ float pacc[3][4][NH][2];            // 6 KB wave partials
    const bool isK = blockIdx.x >= 512;
    const float* __restrict__ in = isK ? key : query;
    const float* __restrict__ W  = isK ? Wk : Wq;
    const int rowbase = (blockIdx.x & 511) * 8;

    {   // stage 8 rows x 256 d, transposed
        const int r = t & 7, c = (t >> 3) * 8;
        const float* src = in + (size_t)(rowbase + r) * ND + c;
        const f32x4 v0 = *(const f32x4*)src;
        const f32x4 v1 = *(const f32x4*)(src + 4);
        insT[c + 0][r] = v0.x; insT[c + 1][r] = v0.y;
        insT[c + 2][r] = v0.z; insT[c + 3][r] = v0.w;
        insT[c + 4][r] = v1.x; insT[c + 5][r] = v1.y;
        insT[c + 6][r] = v1.z; insT[c + 7][r] = v1.w;
    }
    __syncthreads();

    const int lane = t & 63;          // lane = h
    const int w    = t >> 6;          // wave = d-quarter
    const int d0   = w * 64;

    f32x2 acc[4] = {{0.f,0.f},{0.f,0.f},{0.f,0.f},{0.f,0.f}};
    for (int dd = 0; dd < 64; ++dd) {
        const int d = d0 + dd;
        const float wv = W[(size_t)d * NH + lane];         // coalesced L2
        const f32x4 rA = *(const f32x4*)&insT[d][0];       // uniform b128
        const f32x4 rB = *(const f32x4*)&insT[d][4];
        acc[0] = fma2(mk2(rA.x, rA.y), sp2(wv), acc[0]);
        acc[1] = fma2(mk2(rA.z, rA.w), sp2(wv), acc[1]);
        acc[2] = fma2(mk2(rB.x, rB.y), sp2(wv), acc[2]);
        acc[3] = fma2(mk2(rB.z, rB.w), sp2(wv), acc[3]);
    }
    if (w > 0) {
        #pragma unroll
        for (int rp = 0; rp < 4; ++rp)
            *(f32x2*)&pacc[w - 1][rp][lane][0] = acc[rp];
    }
    __syncthreads();
    if (w == 0) {
        float e[8];
        #pragma unroll
        for (int rp = 0; rp < 4; ++rp) {
            f32x2 a = acc[rp];
            a += *(const f32x2*)&pacc[0][rp][lane][0];
            a += *(const f32x2*)&pacc[1][rp][lane][0];
            a += *(const f32x2*)&pacc[2][rp][lane][0];
            e[2 * rp] = a.x; e[2 * rp + 1] = a.y;
        }
        #pragma unroll
        for (int j = 0; j < 8; ++j) {
            const float x = fminf(fmaxf(e[j] * SCALE2, -30.f), 30.f);
            e[j] = EXP2(x);
        }
        if (!isK) {
            const float wx = w_v[lane ^ 1];
            #pragma unroll
            for (int j = 0; j < 8; ++j) {
                const int g = rowbase + j;
                float* dst = qside + ((size_t)g * 16 + (lane >> 2)) * 8 + (lane & 3);
                dst[0] = e[j];
                dst[4] = wx * e[j];
            }
        } else {
            #pragma unroll
            for (int j = 0; j < 8; ++j) {
                const int g = rowbase + j;
                const int bb = g >> 9, kk = g & 511;
                Ekp[((size_t)bb * NH + lane) * NK + kk] = e[j];
            }
        }
    }
    if (blockIdx.x == 0) {
        if (t < 32) w01g[t] = w_v[2 * t] + w_v[2 * t + 1];
        if (t == 64) {
            float s = 0.f;
            for (int h = 0; h < NH; ++h) s += w_v[h];
            wsumg[0] = s;
        }
    }
}

// ---------------- score + softmax -> normalized Ph[b][q][k] f16
// grid = 512 blocks (XCD-swizzled) x 512 thr (8 waves) — the R15-proven shape.
// Thread = 2 adjacent k (kp=t&255) x 4 rows (rh=t>>8), eA/eB rolled prefetch.
__global__ __launch_bounds__(512, 4) void score_kernel(
    const float* __restrict__ qside, const float* __restrict__ Ekp,
    const unsigned char* __restrict__ mask,
    const float* __restrict__ w01g, const float* __restrict__ wsumg,
    _Float16* __restrict__ Ph)
{
    __shared__ float reds[QT][4];

    const int t    = threadIdx.x;
    const int lane = t & 63;
    const int w    = t >> 6;
    // XCD swizzle (512%8==0, bijective): one batch per XCD.
    const int bid  = ((int)(blockIdx.x & 7) << 6) | ((int)blockIdx.x >> 3);
    const int b    = bid >> 6;
    const int q0   = (bid & 63) * QT;
    const int rh   = __builtin_amdgcn_readfirstlane(t >> 8);  // 0/1 -> rows 4rh..
    const int kp   = t & 255;

    const float wsumL = wsumg[0] * LOG2E;
    const float* __restrict__ qs  = qside + (size_t)(b * NQ + q0 + rh * 4) * 128;
    const float* __restrict__ ekc = Ekp + (size_t)b * NH * NK + 2 * kp;

    f32x2 eA[4], eB[4];
    #pragma unroll
    for (int j = 0; j < 4; ++j) eA[j] = *(const f32x2*)&ekc[(size_t)j * NK];
    #pragma unroll
    for (int j = 0; j < 4; ++j) eB[j] = *(const f32x2*)&ekc[(size_t)(4 + j) * NK];

    f32x2 acc[4] = {{0.f,0.f},{0.f,0.f},{0.f,0.f},{0.f,0.f}};

    for (int hc = 0; hc < 16; hc += 2) {
        {   // even chunk: consume eA, prefetch hc+2 into eA
            const f32x2 k0 = eA[0], k1 = eA[1], k2 = eA[2], k3 = eA[3];
            if (hc + 2 < 16) {
                #pragma unroll
                for (int j = 0; j < 4; ++j)
                    eA[j] = *(const f32x2*)&ekc[(size_t)(4 * (hc + 2) + j) * NK];
            }
            const float wa = w01g[2 * hc], wb = w01g[2 * hc + 1];
            #pragma unroll
            for (int r = 0; r < 4; ++r) {
                const f32x4 eqv = *(const f32x4*)&qs[r * 128 + hc * 8];     // s_load
                const f32x4 fqv = *(const f32x4*)&qs[r * 128 + hc * 8 + 4]; // s_load
                score4(k0, k1, k2, k3, eqv, fqv, wa, wb, acc[r]);
            }
        }
        {   // odd chunk: consume eB, prefetch hc+3 into eB
            const f32x2 k0 = eB[0], k1 = eB[1], k2 = eB[2], k3 = eB[3];
            if (hc + 3 < 16) {
                #pragma unroll
                for (int j = 0; j < 4; ++j)
                    eB[j] = *(const f32x2*)&ekc[(size_t)(4 * (hc + 3) + j) * NK];
            }
            const float wa = w01g[2 * hc + 2], wb = w01g[2 * hc + 3];
            #pragma unroll
            for (int r = 0; r < 4; ++r) {
                const f32x4 eqv = *(const f32x4*)&qs[r * 128 + (hc + 1) * 8];
                const f32x4 fqv = *(const f32x4*)&qs[r * 128 + (hc + 1) * 8 + 4];
                score4(k0, k1, k2, k3, eqv, fqv, wa, wb, acc[r]);
            }
        }
    }

    // ---- mask + exp (no max-subtraction: |score| <= sum|w_h| ~ 6.4)
    const unsigned char* __restrict__ mb =
        mask + (size_t)(b * NQ + q0 + rh * 4) * NK + 2 * kp;
    f32x2 p[4];
    #pragma unroll
    for (int r = 0; r < 4; ++r) {
        f32x2 arg = fma2(acc[r], sp2(-2.f * LOG2E), sp2(wsumL));
        const unsigned short m = *(const unsigned short*)(mb + (size_t)r * NK);
        if (m & 0x00ff) arg.x = -__builtin_inff();
        if (m & 0xff00) arg.y = -__builtin_inff();
        p[r] = mk2(EXP2(arg.x), EXP2(arg.y));
    }

    // ---- row sums: wave shuffle + cross-wave LDS (4 k-quarter waves/row)
    #pragma unroll
    for (int r = 0; r < 4; ++r) {
        float s = p[r].x + p[r].y;
        #pragma unroll
        for (int off = 32; off; off >>= 1) s += __shfl_xor(s, off, 64);
        if (lane == 0) reds[rh * 4 + r][w & 3] = s;
    }
    __syncthreads();
    #pragma unroll
    for (int r = 0; r < 4; ++r) {
        const f32x4 sv = *(const f32x4*)&reds[rh * 4 + r][0];
        const float rin = RCP((sv.x + sv.y) + (sv.z + sv.w));
        const f32x2 pn = p[r] * rin;
        *(f16x2*)&Ph[(size_t)(b * NQ + q0 + rh * 4 + r) * NK + 2 * kp] =
            cvt2h(pn.x, pn.y);
    }
}

// ---------------- PV via MFMA f16: O[16 q][256 d] per block.
// grid = 256 blocks (XCD-swizzled) x 512 thr (8 waves); wave = 32 d cols.
// mfma_f32_16x16x32_f16: A = Ph[16 rows][32 k] (lane: row=l&15, k=8*(l>>4)+j),
// B = VhT-slice [32 k][16 d] (lane: col=l&15, same k), both b128 from L2.
// C/D: col=lane&15, row=4*(lane>>4)+i (m89-verified mapping).
__global__ __launch_bounds__(512, 4) void pv_kernel(
    const _Float16* __restrict__ Ph, const _Float16* __restrict__ VhT,
    float* __restrict__ out)
{
    const int t    = threadIdx.x;
    const int lane = t & 63;
    const int w    = t >> 6;                 // 0..7 -> d-block of 32
    // XCD swizzle (256%8==0, bijective): one batch per XCD.
    const int bid  = ((int)(blockIdx.x & 7) << 5) | ((int)blockIdx.x >> 3);
    const int b    = bid >> 5;
    const int q0   = (bid & 31) * 16;
    const int ln   = lane & 15;              // A-row / B-col / D-col
    const int kg   = lane >> 4;              // k-group (8 f16 each)

    const _Float16* __restrict__ pA =
        Ph + (size_t)(b * NQ + q0 + ln) * NK + kg * 8;
    const _Float16* __restrict__ pB0 =
        VhT + (size_t)(b * ND + w * 32 + ln) * NK + kg * 8;
    const _Float16* __restrict__ pB1 = pB0 + (size_t)16 * NK;

    f32x4 c0 = {0.f, 0.f, 0.f, 0.f}, c1 = {0.f, 0.f, 0.f, 0.f};
    f16x8 a  = *(const f16x8*)pA;
    f16x8 b0 = *(const f16x8*)pB0;
    f16x8 b1 = *(const f16x8*)pB1;

    #pragma unroll
    for (int s = 0; s < 16; ++s) {
        f16x8 an = a, b0n = b0, b1n = b1;
        if (s < 15) {   // 1-deep prefetch (immediate-offset loads)
            an  = *(const f16x8*)(pA  + 32 * (s + 1));
            b0n = *(const f16x8*)(pB0 + 32 * (s + 1));
            b1n = *(const f16x8*)(pB1 + 32 * (s + 1));
        }
        c0 = __builtin_amdgcn_mfma_f32_16x16x32_f16(a, b0, c0, 0, 0, 0);
        c1 = __builtin_amdgcn_mfma_f32_16x16x32_f16(a, b1, c1, 0, 0, 0);
        a = an; b0 = b0n; b1 = b1n;
    }

    // ---- store: row = q0 + 4*kg + i, cols 32w+ln and 32w+16+ln
    #pragma unroll
    for (int i = 0; i < 4; ++i) {
        float* __restrict__ o =
            out + (size_t)(b * NQ + q0 + 4 * kg + i) * ND + w * 32 + ln;
        o[0]  = c0[i];
        o[16] = c1[i];
    }
}

extern "C" void kernel_launch(void* const* d_in, const int* in_sizes, int n_in,
                              void* d_out, int out_size, void* d_ws, size_t ws_size,
                              hipStream_t stream) {
    const float* key   = (const float*)d_in[0];
    const float* query = (const float*)d_in[1];
    const float* value = (const float*)d_in[2];
    const unsigned char* mask = (const unsigned char*)d_in[3];
    const float* Wk  = (const float*)d_in[4];
    const float* Wq  = (const float*)d_in[5];
    const float* w_v = (const float*)d_in[6];
    float* out = (float*)d_out;

    float* Ekp   = (float*)d_ws;                        // [NB, NH, NK]    1 MB
    float* qside = Ekp + (size_t)NB * NH * NK;          // [NB*NQ, 128]    2 MB
    float* w01g  = qside + (size_t)NB * NQ * 128;       // [32]
    float* wsumg = w01g + 32;                           // [1]
    _Float16* Ph  = (_Float16*)(w01g + 64);             // [NB, NQ, NK]    4 MB
    _Float16* VhT = Ph + (size_t)NB * NQ * NK;          // [NB, ND, NK]    2 MB

    proj_kernel<<<1536, 256, 0, stream>>>(query, key, value, Wq, Wk, w_v,
                                          qside, Ekp, w01g, wsumg, VhT);
    score_kernel<<<512, 512, 0, stream>>>(qside, Ekp, mask, w01g, wsumg, Ph);
    pv_kernel<<<256, 512, 0, stream>>>(Ph, VhT, out);
}